// Round 4
// baseline (412.896 us; speedup 1.0000x reference)
//
#include <hip/hip_runtime.h>
#include <hip/hip_bf16.h>

#define NTOK 16384
#define SQRT_C 11.313708498984761f
#define QSCALE 0.17677669529663687f
#define ROWP 152   // padded LDS row (shorts): 304 B = 76 dw == 12 banks, 16B-aligned

typedef __attribute__((ext_vector_type(8))) short v8s;   // 8 bf16 (4 VGPRs)
typedef __attribute__((ext_vector_type(4))) short v4s;   // 4 bf16 (8B)
typedef __attribute__((ext_vector_type(4))) float v4f;   // 4 fp32

__device__ inline short f2bf(float f) {
    __hip_bfloat16 h = __float2bfloat16(f);
    return __builtin_bit_cast(short, h);
}
__device__ inline float bf2f(short s) {
    unsigned u = ((unsigned)(unsigned short)s) << 16;
    return __builtin_bit_cast(float, u);
}
// LDS-only barrier: orders ds ops across waves WITHOUT draining vmcnt,
// so register prefetch of x stays in flight across tile boundaries.
__device__ inline void lds_barrier() {
    __builtin_amdgcn_sched_barrier(0);
    asm volatile("s_waitcnt lgkmcnt(0)" ::: "memory");
    __builtin_amdgcn_s_barrier();
    __builtin_amdgcn_sched_barrier(0);
}

// ---------------- K0: wbf[o][c] = bf16(w_qkv[o][c] * g1[c])  (g1 folded) -------
__global__ void k0_cvt(const float* __restrict__ wq, const float* __restrict__ g1,
                       short* __restrict__ wbf) {
    int i = blockIdx.x * 256 + threadIdx.x;   // 49152
    wbf[i] = f2bf(wq[i] * g1[i & 127]);
}

// ---------------- K1: qkv MFMA, W STREAMED from L2 (no 96-reg preload) ---------
// grid 1024 = 16 b x 64 chunks of 256 tokens; 256 thr (4 waves); 8 tiles of 32 t.
// Total regs (VGPR+AGPR unified) capped at 128 via (256,4) -> 4 blocks/CU.
// W fragments streamed per pr-group (32 regs single-buffered); x prefetch issued
// AFTER pr2's W loads so W-waits are vmcnt(4), never draining the x loads.
__global__ __launch_bounds__(256, 4) void k1_qkv(
    const float* __restrict__ x, const short* __restrict__ wbf,
    short* __restrict__ qfrag, float* __restrict__ pS, float* __restrict__ pC)
{
    __shared__ __align__(16) short xn[32][ROWP];    // bf16(x) [t][c]
    __shared__ __align__(16) short kvbuf[256][40];  // exp(k) rows 0..127, v rows 128..255
    __shared__ __align__(16) short qbufT[32][ROWP]; // q_soft bf16 [t][c]  (transposed)
    __shared__ __align__(16) float nrm[4][32];      // per-wave sumsq partials

    const int tid = threadIdx.x;
    const int lane = tid & 63;
    const int w = tid >> 6;
    const int qd = lane >> 4;          // quad 0..3
    const int lm = lane & 15;
    const int b = blockIdx.x >> 6;
    const int chunk = blockIdx.x & 63;
    const size_t xbase = (size_t)b * 128 * NTOK;
    const int crow = tid >> 3;         // channel sub-row 0..31
    const int tq4 = (tid & 7) * 4;     // token offset within tile

    // per-lane W fragment base: row (96w + lm), col qd*8; frag (rg,kk) at
    // +rg*16*128 + kk*32 (compile-time offsets after unroll)
    const short* wb = wbf + (96 * w + lm) * 128 + qd * 8;

    v4f cacc[2][2];
    #pragma unroll
    for (int i = 0; i < 2; ++i)
        #pragma unroll
        for (int j = 0; j < 2; ++j)
            cacc[i][j] = (v4f){0.f, 0.f, 0.f, 0.f};
    float accSr[4][4] = {};            // in-reg exp(k) row sums (4 k-rgs max/wave)

    // x register buffer: thread holds channels {32p+crow}, tokens tq4..tq4+3
    v4f xv[4];
    auto loadx = [&](int tt) {
        #pragma unroll
        for (int p = 0; p < 4; ++p)
            xv[p] = *(const v4f*)(x + xbase + (size_t)(p * 32 + crow) * NTOK + tt + tq4);
    };
    loadx(chunk * 256);                // prologue prefetch (tile 0)

    for (int st = 0; st < 8; ++st) {
        const int t0 = chunk * 256 + st * 32;

        // ---- (a) sumsq reduce + bf16 convert ----
        float s[4];
        #pragma unroll
        for (int j = 0; j < 4; ++j) {
            float acc = 0.f;
            #pragma unroll
            for (int p = 0; p < 4; ++p) { float v = xv[p][j]; acc += v * v; }
            s[j] = acc;
        }
        #pragma unroll
        for (int j = 0; j < 4; ++j) {
            s[j] += __shfl_xor(s[j], 8, 64);
            s[j] += __shfl_xor(s[j], 16, 64);
            s[j] += __shfl_xor(s[j], 32, 64);
        }
        if (lane < 8) *(v4f*)&nrm[w][lane * 4] = (v4f){s[0], s[1], s[2], s[3]};
        #pragma unroll
        for (int p = 0; p < 4; ++p)
            #pragma unroll
            for (int j = 0; j < 4; ++j)
                xn[tq4 + j][p * 32 + crow] = f2bf(xv[p][j]);
        lds_barrier();

        // per-token rms scale for this lane's two columns (t = lm, 16+lm)
        float sA = nrm[0][lm] + nrm[1][lm] + nrm[2][lm] + nrm[3][lm];
        float sB = nrm[0][16 + lm] + nrm[1][16 + lm] + nrm[2][16 + lm] + nrm[3][16 + lm];
        float scl0 = SQRT_C / fmaxf(sqrtf(sA), 1e-12f);
        float scl1 = SQRT_C / fmaxf(sqrtf(sB), 1e-12f);

        // ---- (b) per pr-group: stream W frags, MFMA K=128, distribute ----
        #pragma unroll
        for (int pr = 0; pr < 3; ++pr) {
            const int R = 96 * w + 32 * pr;
            v8s Wf[2][4];
            #pragma unroll
            for (int f = 0; f < 2; ++f)
                #pragma unroll
                for (int kk = 0; kk < 4; ++kk)
                    Wf[f][kk] = *(const v8s*)(wb + (2 * pr + f) * 2048 + kk * 32);
            if (pr == 2 && st < 7) loadx(t0 + 32);   // x prefetch AFTER W issue

            v4f C2[2][2];
            #pragma unroll
            for (int f = 0; f < 2; ++f) {
                C2[f][0] = (v4f){0.f, 0.f, 0.f, 0.f};
                C2[f][1] = (v4f){0.f, 0.f, 0.f, 0.f};
            }
            #pragma unroll
            for (int kk = 0; kk < 4; ++kk) {
                v8s B0 = *(const v8s*)&xn[lm][kk * 32 + qd * 8];
                v8s B1 = *(const v8s*)&xn[16 + lm][kk * 32 + qd * 8];
                #pragma unroll
                for (int f = 0; f < 2; ++f) {
                    C2[f][0] = __builtin_amdgcn_mfma_f32_16x16x32_bf16(Wf[f][kk], B0, C2[f][0], 0, 0, 0);
                    C2[f][1] = __builtin_amdgcn_mfma_f32_16x16x32_bf16(Wf[f][kk], B1, C2[f][1], 0, 0, 0);
                }
            }

            if (R < 128) {                      // q head (rows R..R+31), softmax over d
                #pragma unroll
                for (int tg = 0; tg < 2; ++tg) {
                    const float sclt = tg ? scl1 : scl0;
                    float e0[4], e1[4];
                    float m = -1e30f;
                    #pragma unroll
                    for (int r = 0; r < 4; ++r) {
                        e0[r] = C2[0][tg][r] * sclt;
                        e1[r] = C2[1][tg][r] * sclt;
                        m = fmaxf(m, fmaxf(e0[r], e1[r]));
                    }
                    m = fmaxf(m, __shfl_xor(m, 16, 64));
                    m = fmaxf(m, __shfl_xor(m, 32, 64));
                    float ssum = 0.f;
                    #pragma unroll
                    for (int r = 0; r < 4; ++r) {
                        e0[r] = __expf(e0[r] - m);
                        e1[r] = __expf(e1[r] - m);
                        ssum += e0[r] + e1[r];
                    }
                    ssum += __shfl_xor(ssum, 16, 64);
                    ssum += __shfl_xor(ssum, 32, 64);
                    const float inv = QSCALE / ssum;
                    const int t = tg * 16 + lm;
                    v4s p0, p1;
                    #pragma unroll
                    for (int r = 0; r < 4; ++r) {
                        p0[r] = f2bf(e0[r] * inv);
                        p1[r] = f2bf(e1[r] * inv);
                    }
                    *(v4s*)&qbufT[t][R + qd * 4] = p0;
                    *(v4s*)&qbufT[t][R + 16 + qd * 4] = p1;
                }
            } else {                            // k or v rows
                #pragma unroll
                for (int f = 0; f < 2; ++f) {
                    const int R2 = R + 16 * f;
                    const bool isk = (R2 < 256);
                    float part[4] = {0.f, 0.f, 0.f, 0.f};
                    #pragma unroll
                    for (int tg = 0; tg < 2; ++tg) {
                        const float sclt = tg ? scl1 : scl0;
                        const int col = tg * 16 + lm;
                        #pragma unroll
                        for (int r = 0; r < 4; ++r) {
                            float val = C2[f][tg][r] * sclt;
                            if (isk) val = __expf(val);
                            short vb = f2bf(val);
                            kvbuf[R2 - 128 + qd * 4 + r][col] = vb;
                            if (isk) part[r] += bf2f(vb);
                        }
                    }
                    if (isk) {                  // in-reg row-sum of exp(k)
                        #pragma unroll
                        for (int r = 0; r < 4; ++r) {
                            float p = part[r];
                            p += __shfl_xor(p, 1, 64);
                            p += __shfl_xor(p, 2, 64);
                            p += __shfl_xor(p, 4, 64);
                            p += __shfl_xor(p, 8, 64);
                            // compile-time accSr indices (rule: no runtime idx)
                            if (w == 1) {
                                if (2 * pr + f >= 2) accSr[(2 * pr + f - 2) & 3][r] += p;
                            } else {
                                accSr[(2 * pr + f) & 3][r] += p;
                            }
                        }
                    }
                }
            }
        }
        lds_barrier();

        // ---- (c) q gather -> global qfrag (vectorized) + context MFMA ----
        {
            const int tb0 = chunk * 16 + st * 2;
            #pragma unroll
            for (int tbl = 0; tbl < 2; ++tbl) {
                v8s pk = *(const v8s*)&qbufT[tbl * 16 + lm][w * 32 + qd * 8];
                *(v8s*)(qfrag + ((((size_t)b * 1024 + tb0 + tbl) * 4 + w) << 9) + lane * 8) = pk;
            }
            v8s A0 = *(const v8s*)&kvbuf[w * 32 + lm][qd * 8];
            v8s A1 = *(const v8s*)&kvbuf[w * 32 + 16 + lm][qd * 8];
            v8s B0 = *(const v8s*)&kvbuf[128 + w * 32 + lm][qd * 8];
            v8s B1 = *(const v8s*)&kvbuf[128 + w * 32 + 16 + lm][qd * 8];
            cacc[0][0] = __builtin_amdgcn_mfma_f32_16x16x32_bf16(A0, B0, cacc[0][0], 0, 0, 0);
            cacc[0][1] = __builtin_amdgcn_mfma_f32_16x16x32_bf16(A0, B1, cacc[0][1], 0, 0, 0);
            cacc[1][0] = __builtin_amdgcn_mfma_f32_16x16x32_bf16(A1, B0, cacc[1][0], 0, 0, 0);
            cacc[1][1] = __builtin_amdgcn_mfma_f32_16x16x32_bf16(A1, B1, cacc[1][1], 0, 0, 0);
        }
    }

    // epilogue: exp(k) row sums (wave1 holds k rows 0..63, wave2 rows 64..127)
    if ((w == 1 || w == 2) && lm == 0) {
        const int base = (w == 1) ? 0 : 64;
        #pragma unroll
        for (int i = 0; i < 4; ++i)
            #pragma unroll
            for (int r = 0; r < 4; ++r)
                pS[(size_t)(b * 64 + chunk) * 128 + base + i * 16 + qd * 4 + r] = accSr[i][r];
    }
    #pragma unroll
    for (int dg = 0; dg < 2; ++dg)
        #pragma unroll
        for (int eg = 0; eg < 2; ++eg)
            #pragma unroll
            for (int r = 0; r < 4; ++r) {
                int d = dg * 16 + qd * 4 + r;
                int e = eg * 16 + lm;
                pC[(size_t)(b * 64 + chunk) * 4096 + w * 1024 + d * 32 + e] = cacc[dg][eg][r];
            }
}

// ---------------- K2: reduce partials -> ctx -> MgT bf16 [b][o][c'] -------------
// grid 256 = 16 b x 4 h x 4 de-quarters
__global__ void k2_ctx(const float* __restrict__ pS, const float* __restrict__ pC,
                       const float* __restrict__ wout, short* __restrict__ MgT) {
    __shared__ float ctxq[8][33];
    __shared__ float Sv[32];
    const int tid = threadIdx.x;
    const int blk = blockIdx.x;
    const int qt = blk & 3, h = (blk >> 2) & 3, b = blk >> 4;
    if (tid < 32) {
        float s = 0.f;
        for (int ch = 0; ch < 64; ++ch) s += pS[(size_t)(b * 64 + ch) * 128 + h * 32 + tid];
        Sv[tid] = s;
    }
    __syncthreads();
    {
        int de = qt * 256 + tid;
        float s = 0.f;
        for (int ch = 0; ch < 64; ++ch) s += pC[(size_t)(b * 64 + ch) * 4096 + h * 1024 + de];
        ctxq[tid >> 5][tid & 31] = s / Sv[de >> 5];
    }
    __syncthreads();
    // MgT[o][h*32 + qt*8 + dl] = sum_e wout[o][h*32+e] * ctxq[dl][e]
    #pragma unroll
    for (int k = 0; k < 4; ++k) {
        int idx = tid + k * 256;           // 0..1023
        int o = idx >> 3, dl = idx & 7;
        float m = 0.f;
        #pragma unroll
        for (int e = 0; e < 32; ++e) m += wout[o * 128 + h * 32 + e] * ctxq[dl][e];
        MgT[((size_t)b * 128 + o) * 128 + h * 32 + qt * 8 + dl] = f2bf(m);
    }
}

// ---------------- K3: y = M_b @ q_soft + b_out -> rmsnorm(g2) (MFMA) ------------
// grid 2048 = 16 b x 128 chunks of 128 tokens; wave w owns rows 32w..32w+31.
// Tokens processed in 2 halves of 64 (C[2][4]=32 regs) -> total regs <=128,
// (256,4) -> 4 waves/SIMD.
__global__ __launch_bounds__(256, 4) void k3_out(
    const short* __restrict__ qfrag, const short* __restrict__ MgT,
    const float* __restrict__ bo, const float* __restrict__ g2,
    float* __restrict__ out)
{
    __shared__ float part[4][64];
    __shared__ float scl[64];
    const int tid = threadIdx.x;
    const int lane = tid & 63, w = tid >> 6;
    const int qd = lane >> 4, lm = lane & 15;
    const int b = blockIdx.x >> 7;
    const int t0 = (blockIdx.x & 127) << 7;
    const int tb0 = t0 >> 4;

    v8s A[2][4];
    #pragma unroll
    for (int rg = 0; rg < 2; ++rg)
        #pragma unroll
        for (int kk = 0; kk < 4; ++kk)
            A[rg][kk] = *(const v8s*)(MgT + ((size_t)b * 128 + 32 * w + rg * 16 + lm) * 128 + kk * 32 + qd * 8);

    float bov[2][4], g2v[2][4];
    #pragma unroll
    for (int rg = 0; rg < 2; ++rg)
        #pragma unroll
        for (int r = 0; r < 4; ++r) {
            int o = 32 * w + rg * 16 + qd * 4 + r;
            bov[rg][r] = bo[o];
            g2v[rg][r] = g2[o];
        }

    #pragma unroll
    for (int hb = 0; hb < 2; ++hb) {
        v4f C[2][4];
        #pragma unroll
        for (int rg = 0; rg < 2; ++rg)
            #pragma unroll
            for (int tbl = 0; tbl < 4; ++tbl)
                C[rg][tbl] = (v4f){0.f, 0.f, 0.f, 0.f};

        #pragma unroll
        for (int tbl = 0; tbl < 4; ++tbl) {
            const int tb = hb * 4 + tbl;
            #pragma unroll
            for (int kk = 0; kk < 4; ++kk) {
                v8s B = *(const v8s*)(qfrag + ((((size_t)b * 1024 + tb0 + tb) * 4 + kk) << 9) + lane * 8);
                C[0][tbl] = __builtin_amdgcn_mfma_f32_16x16x32_bf16(A[0][kk], B, C[0][tbl], 0, 0, 0);
                C[1][tbl] = __builtin_amdgcn_mfma_f32_16x16x32_bf16(A[1][kk], B, C[1][tbl], 0, 0, 0);
            }
        }

        // bias + per-token sumsq (xor shuffles + cross-wave LDS)
        #pragma unroll
        for (int tbl = 0; tbl < 4; ++tbl) {
            float ss = 0.f;
            #pragma unroll
            for (int rg = 0; rg < 2; ++rg)
                #pragma unroll
                for (int r = 0; r < 4; ++r) {
                    C[rg][tbl][r] += bov[rg][r];
                    ss += C[rg][tbl][r] * C[rg][tbl][r];
                }
            ss += __shfl_xor(ss, 16, 64);
            ss += __shfl_xor(ss, 32, 64);
            if (lane < 16) part[w][tbl * 16 + lane] = ss;
        }
        __syncthreads();
        if (tid < 64) {
            float s = part[0][tid] + part[1][tid] + part[2][tid] + part[3][tid];
            scl[tid] = SQRT_C / fmaxf(sqrtf(s), 1e-12f);
        }
        __syncthreads();
        #pragma unroll
        for (int tbl = 0; tbl < 4; ++tbl) {
            float sc = scl[tbl * 16 + lm];
            #pragma unroll
            for (int rg = 0; rg < 2; ++rg)
                #pragma unroll
                for (int r = 0; r < 4; ++r) {
                    int o = 32 * w + rg * 16 + qd * 4 + r;
                    out[((size_t)b * 128 + o) * NTOK + t0 + (hb * 4 + tbl) * 16 + lm] = C[rg][tbl][r] * sc * g2v[rg][r];
                }
        }
        if (hb == 0) __syncthreads();   // scl/part reuse fence between halves
    }
}

extern "C" void kernel_launch(void* const* d_in, const int* in_sizes, int n_in,
                              void* d_out, int out_size, void* d_ws, size_t ws_size,
                              hipStream_t stream) {
    const float* x    = (const float*)d_in[0];
    const float* g1   = (const float*)d_in[1];
    const float* wqkv = (const float*)d_in[2];
    const float* wout = (const float*)d_in[3];
    const float* bo   = (const float*)d_in[4];
    const float* g2   = (const float*)d_in[5];
    float* out = (float*)d_out;
    char* ws = (char*)d_ws;
    // ws: qfrag bf16 [16][1024][4][512] @0 (67,108,864 B)
    //     pS fp32 [16][64][128]  @67,108,864 (524,288)
    //     pC fp32 [16][64][4096] @67,633,152 (16,777,216)
    //     MgT bf16 [16][128][128] @84,410,368 (524,288)
    //     wbf bf16 [384][128]     @84,934,656 (98,304)   total 85,032,960 B
    short* qfrag = (short*)ws;
    float* pS = (float*)(ws + 67108864);
    float* pC = (float*)(ws + 67633152);
    short* MgT = (short*)(ws + 84410368);
    short* wbf = (short*)(ws + 84934656);

    k0_cvt<<<192, 256, 0, stream>>>(wqkv, g1, wbf);
    k1_qkv<<<1024, 256, 0, stream>>>(x, wbf, qfrag, pS, pC);
    k2_ctx<<<256, 256, 0, stream>>>(pS, pC, wout, MgT);
    k3_out<<<2048, 256, 0, stream>>>(qfrag, MgT, bo, g2, out);
}

// Round 5
// 349.182 us; speedup vs baseline: 1.1825x; 1.1825x over previous
//
#include <hip/hip_runtime.h>
#include <hip/hip_bf16.h>

#define NTOK 16384
#define SQRT_C 11.313708498984761f
#define QSCALE 0.17677669529663687f
#define ROWP 152   // padded LDS row (shorts): 304 B = 76 dw == 12 banks, 16B-aligned

typedef __attribute__((ext_vector_type(8))) short v8s;   // 8 bf16 (4 VGPRs)
typedef __attribute__((ext_vector_type(4))) short v4s;   // 4 bf16 (8B)
typedef __attribute__((ext_vector_type(4))) float v4f;   // 4 fp32

__device__ inline short f2bf(float f) {
    __hip_bfloat16 h = __float2bfloat16(f);
    return __builtin_bit_cast(short, h);
}
__device__ inline float bf2f(short s) {
    unsigned u = ((unsigned)(unsigned short)s) << 16;
    return __builtin_bit_cast(float, u);
}
// LDS-only barrier: orders ds ops across waves WITHOUT draining vmcnt,
// so in-flight global loads stay outstanding across tile boundaries.
__device__ inline void lds_barrier() {
    __builtin_amdgcn_sched_barrier(0);
    asm volatile("s_waitcnt lgkmcnt(0)" ::: "memory");
    __builtin_amdgcn_s_barrier();
    __builtin_amdgcn_sched_barrier(0);
}

// ---------------- K0: wbf[o][c] = bf16(w_qkv[o][c] * g1[c])  (g1 folded) -------
__global__ void k0_cvt(const float* __restrict__ wq, const float* __restrict__ g1,
                       short* __restrict__ wbf) {
    int i = blockIdx.x * 256 + threadIdx.x;   // 49152
    wbf[i] = f2bf(wq[i] * g1[i & 127]);
}

// ---------------- K1: qkv MFMA, W streamed, phase-(a) software-pipelined -------
// grid 1024 = 16 b x 64 chunks of 256 tokens; 256 thr (4 waves); 8 tiles of 32 t.
// (256,2): cap 256 total regs -> NO spills (R2/R4 showed (256,4) forces arch=64
// and spills; occupancy stays 2 blocks/CU). Win here = critical-path: phase (a)
// of tile t+1 (sumsq shfl chain + f2bf + LDS stage, double-buffered xn/nrm)
// executes inside the (b)-region of tile t, off the serial path.
__global__ __launch_bounds__(256, 2) void k1_qkv(
    const float* __restrict__ x, const short* __restrict__ wbf,
    short* __restrict__ qfrag, float* __restrict__ pS, float* __restrict__ pC)
{
    __shared__ __align__(16) short xn[2][32][ROWP]; // bf16(x) [buf][t][c]  (19.5 KB)
    __shared__ __align__(16) short kvbuf[256][40];  // exp(k) 0..127, v 128..255 (20.5 KB)
    __shared__ __align__(16) short qbufT[32][ROWP]; // q_soft bf16 [t][c]    (9.7 KB)
    __shared__ __align__(16) float nrm[2][4][32];   // per-wave sumsq partials (1 KB)

    const int tid = threadIdx.x;
    const int lane = tid & 63;
    const int w = tid >> 6;
    const int qd = lane >> 4;          // quad 0..3
    const int lm = lane & 15;
    const int b = blockIdx.x >> 6;
    const int chunk = blockIdx.x & 63;
    const size_t xbase = (size_t)b * 128 * NTOK;
    const int crow = tid >> 3;         // channel sub-row 0..31
    const int tq4 = (tid & 7) * 4;     // token offset within tile

    // per-lane W fragment base: row (96w + lm), col qd*8; frag (rg,kk) at
    // +rg*2048 + kk*32 (compile-time offsets after unroll)
    const short* wb = wbf + (96 * w + lm) * 128 + qd * 8;

    v4f cacc[2][2];
    #pragma unroll
    for (int i = 0; i < 2; ++i)
        #pragma unroll
        for (int j = 0; j < 2; ++j)
            cacc[i][j] = (v4f){0.f, 0.f, 0.f, 0.f};
    float accSr[4][4] = {};            // in-reg exp(k) row sums (4 k-rgs max/wave)

    // x register buffer: thread holds channels {32p+crow}, tokens tq4..tq4+3
    v4f xv[4];
    auto loadx = [&](int tt) {
        #pragma unroll
        for (int p = 0; p < 4; ++p)
            xv[p] = *(const v4f*)(x + xbase + (size_t)(p * 32 + crow) * NTOK + tt + tq4);
    };

    // phase (a): consume xv -> nrm[buf], xn[buf]; then issue next x load
    auto do_a = [&](int tile, int buf) {
        float s[4];
        #pragma unroll
        for (int j = 0; j < 4; ++j) {
            float acc = 0.f;
            #pragma unroll
            for (int p = 0; p < 4; ++p) { float v = xv[p][j]; acc += v * v; }
            s[j] = acc;
        }
        #pragma unroll
        for (int j = 0; j < 4; ++j) {
            s[j] += __shfl_xor(s[j], 8, 64);
            s[j] += __shfl_xor(s[j], 16, 64);
            s[j] += __shfl_xor(s[j], 32, 64);
        }
        if (lane < 8) *(v4f*)&nrm[buf][w][lane * 4] = (v4f){s[0], s[1], s[2], s[3]};
        #pragma unroll
        for (int p = 0; p < 4; ++p)
            #pragma unroll
            for (int j = 0; j < 4; ++j)
                xn[buf][tq4 + j][p * 32 + crow] = f2bf(xv[p][j]);
        if (tile + 1 < 8) loadx(chunk * 256 + (tile + 1) * 32);
    };

    loadx(chunk * 256);
    do_a(0, 0);                        // prologue: tile 0 into buf 0 (+issues tile1 load)

    for (int st = 0; st < 8; ++st) {
        const int cur = st & 1;
        const int t0 = chunk * 256 + st * 32;
        (void)t0;
        lds_barrier();

        // per-token rms scale for this lane's two columns (t = lm, 16+lm)
        float sA = nrm[cur][0][lm] + nrm[cur][1][lm] + nrm[cur][2][lm] + nrm[cur][3][lm];
        float sB = nrm[cur][0][16 + lm] + nrm[cur][1][16 + lm] + nrm[cur][2][16 + lm] + nrm[cur][3][16 + lm];
        float scl0 = SQRT_C / fmaxf(sqrtf(sA), 1e-12f);
        float scl1 = SQRT_C / fmaxf(sqrtf(sB), 1e-12f);

        // ---- (b) per pr-group: stream W frags, MFMA K=128, distribute ----
        #pragma unroll
        for (int pr = 0; pr < 3; ++pr) {
            const int R = 96 * w + 32 * pr;
            v8s Wf[2][4];
            #pragma unroll
            for (int f = 0; f < 2; ++f)
                #pragma unroll
                for (int kk = 0; kk < 4; ++kk)
                    Wf[f][kk] = *(const v8s*)(wb + (2 * pr + f) * 2048 + kk * 32);

            v4f C2[2][2];
            #pragma unroll
            for (int f = 0; f < 2; ++f) {
                C2[f][0] = (v4f){0.f, 0.f, 0.f, 0.f};
                C2[f][1] = (v4f){0.f, 0.f, 0.f, 0.f};
            }
            #pragma unroll
            for (int kk = 0; kk < 4; ++kk) {
                v8s B0 = *(const v8s*)&xn[cur][lm][kk * 32 + qd * 8];
                v8s B1 = *(const v8s*)&xn[cur][16 + lm][kk * 32 + qd * 8];
                #pragma unroll
                for (int f = 0; f < 2; ++f) {
                    C2[f][0] = __builtin_amdgcn_mfma_f32_16x16x32_bf16(Wf[f][kk], B0, C2[f][0], 0, 0, 0);
                    C2[f][1] = __builtin_amdgcn_mfma_f32_16x16x32_bf16(Wf[f][kk], B1, C2[f][1], 0, 0, 0);
                }
            }

            if (R < 128) {                      // q head (rows R..R+31), softmax over d
                #pragma unroll
                for (int tg = 0; tg < 2; ++tg) {
                    const float sclt = tg ? scl1 : scl0;
                    float e0[4], e1[4];
                    float m = -1e30f;
                    #pragma unroll
                    for (int r = 0; r < 4; ++r) {
                        e0[r] = C2[0][tg][r] * sclt;
                        e1[r] = C2[1][tg][r] * sclt;
                        m = fmaxf(m, fmaxf(e0[r], e1[r]));
                    }
                    m = fmaxf(m, __shfl_xor(m, 16, 64));
                    m = fmaxf(m, __shfl_xor(m, 32, 64));
                    float ssum = 0.f;
                    #pragma unroll
                    for (int r = 0; r < 4; ++r) {
                        e0[r] = __expf(e0[r] - m);
                        e1[r] = __expf(e1[r] - m);
                        ssum += e0[r] + e1[r];
                    }
                    ssum += __shfl_xor(ssum, 16, 64);
                    ssum += __shfl_xor(ssum, 32, 64);
                    const float inv = QSCALE / ssum;
                    const int t = tg * 16 + lm;
                    v4s p0, p1;
                    #pragma unroll
                    for (int r = 0; r < 4; ++r) {
                        p0[r] = f2bf(e0[r] * inv);
                        p1[r] = f2bf(e1[r] * inv);
                    }
                    *(v4s*)&qbufT[t][R + qd * 4] = p0;
                    *(v4s*)&qbufT[t][R + 16 + qd * 4] = p1;
                }
            } else {                            // k or v rows
                #pragma unroll
                for (int f = 0; f < 2; ++f) {
                    const int R2 = R + 16 * f;
                    const bool isk = (R2 < 256);
                    float part[4] = {0.f, 0.f, 0.f, 0.f};
                    #pragma unroll
                    for (int tg = 0; tg < 2; ++tg) {
                        const float sclt = tg ? scl1 : scl0;
                        const int col = tg * 16 + lm;
                        #pragma unroll
                        for (int r = 0; r < 4; ++r) {
                            float val = C2[f][tg][r] * sclt;
                            if (isk) val = __expf(val);
                            short vb = f2bf(val);
                            kvbuf[R2 - 128 + qd * 4 + r][col] = vb;
                            if (isk) part[r] += bf2f(vb);
                        }
                    }
                    if (isk) {                  // in-reg row-sum of exp(k)
                        #pragma unroll
                        for (int r = 0; r < 4; ++r) {
                            float p = part[r];
                            p += __shfl_xor(p, 1, 64);
                            p += __shfl_xor(p, 2, 64);
                            p += __shfl_xor(p, 4, 64);
                            p += __shfl_xor(p, 8, 64);
                            // compile-time accSr indices (rule: no runtime idx)
                            if (w == 1) {
                                if (2 * pr + f >= 2) accSr[(2 * pr + f - 2) & 3][r] += p;
                            } else {
                                accSr[(2 * pr + f) & 3][r] += p;
                            }
                        }
                    }
                }
            }
        }
        // phase (a) of NEXT tile, co-scheduled with this region (off critical path)
        if (st < 7) do_a(st + 1, cur ^ 1);
        lds_barrier();

        // ---- (c) q gather -> global qfrag (vectorized) + context MFMA ----
        {
            const int tb0 = chunk * 16 + st * 2;
            #pragma unroll
            for (int tbl = 0; tbl < 2; ++tbl) {
                v8s pk = *(const v8s*)&qbufT[tbl * 16 + lm][w * 32 + qd * 8];
                *(v8s*)(qfrag + ((((size_t)b * 1024 + tb0 + tbl) * 4 + w) << 9) + lane * 8) = pk;
            }
            v8s A0 = *(const v8s*)&kvbuf[w * 32 + lm][qd * 8];
            v8s A1 = *(const v8s*)&kvbuf[w * 32 + 16 + lm][qd * 8];
            v8s B0 = *(const v8s*)&kvbuf[128 + w * 32 + lm][qd * 8];
            v8s B1 = *(const v8s*)&kvbuf[128 + w * 32 + 16 + lm][qd * 8];
            cacc[0][0] = __builtin_amdgcn_mfma_f32_16x16x32_bf16(A0, B0, cacc[0][0], 0, 0, 0);
            cacc[0][1] = __builtin_amdgcn_mfma_f32_16x16x32_bf16(A0, B1, cacc[0][1], 0, 0, 0);
            cacc[1][0] = __builtin_amdgcn_mfma_f32_16x16x32_bf16(A1, B0, cacc[1][0], 0, 0, 0);
            cacc[1][1] = __builtin_amdgcn_mfma_f32_16x16x32_bf16(A1, B1, cacc[1][1], 0, 0, 0);
        }
    }

    // epilogue: exp(k) row sums (wave1 holds k rows 0..63, wave2 rows 64..127)
    if ((w == 1 || w == 2) && lm == 0) {
        const int base = (w == 1) ? 0 : 64;
        #pragma unroll
        for (int i = 0; i < 4; ++i)
            #pragma unroll
            for (int r = 0; r < 4; ++r)
                pS[(size_t)(b * 64 + chunk) * 128 + base + i * 16 + qd * 4 + r] = accSr[i][r];
    }
    #pragma unroll
    for (int dg = 0; dg < 2; ++dg)
        #pragma unroll
        for (int eg = 0; eg < 2; ++eg)
            #pragma unroll
            for (int r = 0; r < 4; ++r) {
                int d = dg * 16 + qd * 4 + r;
                int e = eg * 16 + lm;
                pC[(size_t)(b * 64 + chunk) * 4096 + w * 1024 + d * 32 + e] = cacc[dg][eg][r];
            }
}

// ---------------- K2: reduce partials -> ctx -> MgT bf16 [b][o][c'] -------------
// grid 256 = 16 b x 4 h x 4 de-quarters
__global__ void k2_ctx(const float* __restrict__ pS, const float* __restrict__ pC,
                       const float* __restrict__ wout, short* __restrict__ MgT) {
    __shared__ float ctxq[8][33];
    __shared__ float Sv[32];
    const int tid = threadIdx.x;
    const int blk = blockIdx.x;
    const int qt = blk & 3, h = (blk >> 2) & 3, b = blk >> 4;
    if (tid < 32) {
        float s = 0.f;
        for (int ch = 0; ch < 64; ++ch) s += pS[(size_t)(b * 64 + ch) * 128 + h * 32 + tid];
        Sv[tid] = s;
    }
    __syncthreads();
    {
        int de = qt * 256 + tid;
        float s = 0.f;
        for (int ch = 0; ch < 64; ++ch) s += pC[(size_t)(b * 64 + ch) * 4096 + h * 1024 + de];
        ctxq[tid >> 5][tid & 31] = s / Sv[de >> 5];
    }
    __syncthreads();
    // MgT[o][h*32 + qt*8 + dl] = sum_e wout[o][h*32+e] * ctxq[dl][e]
    #pragma unroll
    for (int k = 0; k < 4; ++k) {
        int idx = tid + k * 256;           // 0..1023
        int o = idx >> 3, dl = idx & 7;
        float m = 0.f;
        #pragma unroll
        for (int e = 0; e < 32; ++e) m += wout[o * 128 + h * 32 + e] * ctxq[dl][e];
        MgT[((size_t)b * 128 + o) * 128 + h * 32 + qt * 8 + dl] = f2bf(m);
    }
}

// ---------------- K3: y = M_b @ q_soft + b_out -> rmsnorm(g2) (MFMA) ------------
// grid 2048 = 16 b x 128 chunks of 128 tokens; wave w owns rows 32w..32w+31.
// Two halves of 64 tokens; result staged through LDS [128][68] f32 so HBM
// writes are 256 B-contiguous per 16-lane group (was 64 B scattered).
// (256,2): cap 256 regs, no spill risk; LDS 36 KB limits to 4 blocks/CU.
__global__ __launch_bounds__(256, 2) void k3_out(
    const short* __restrict__ qfrag, const short* __restrict__ MgT,
    const float* __restrict__ bo, const float* __restrict__ g2,
    float* __restrict__ out)
{
    __shared__ __align__(16) float ldsT[128][68];   // 34,816 B (row 272 B)
    __shared__ float part[4][64];
    __shared__ float scl[64];
    const int tid = threadIdx.x;
    const int lane = tid & 63, w = tid >> 6;
    const int qd = lane >> 4, lm = lane & 15;
    const int b = blockIdx.x >> 7;
    const int t0 = (blockIdx.x & 127) << 7;
    const int tb0 = t0 >> 4;

    v8s A[2][4];
    #pragma unroll
    for (int rg = 0; rg < 2; ++rg)
        #pragma unroll
        for (int kk = 0; kk < 4; ++kk)
            A[rg][kk] = *(const v8s*)(MgT + ((size_t)b * 128 + 32 * w + rg * 16 + lm) * 128 + kk * 32 + qd * 8);

    float bov[2][4], g2v[2][4];
    #pragma unroll
    for (int rg = 0; rg < 2; ++rg)
        #pragma unroll
        for (int r = 0; r < 4; ++r) {
            int o = 32 * w + rg * 16 + qd * 4 + r;
            bov[rg][r] = bo[o];
            g2v[rg][r] = g2[o];
        }

    #pragma unroll
    for (int hb = 0; hb < 2; ++hb) {
        v4f C[2][4];
        #pragma unroll
        for (int rg = 0; rg < 2; ++rg)
            #pragma unroll
            for (int tbl = 0; tbl < 4; ++tbl)
                C[rg][tbl] = (v4f){0.f, 0.f, 0.f, 0.f};

        #pragma unroll
        for (int tbl = 0; tbl < 4; ++tbl) {
            const int tb = hb * 4 + tbl;
            #pragma unroll
            for (int kk = 0; kk < 4; ++kk) {
                v8s B = *(const v8s*)(qfrag + ((((size_t)b * 1024 + tb0 + tb) * 4 + kk) << 9) + lane * 8);
                C[0][tbl] = __builtin_amdgcn_mfma_f32_16x16x32_bf16(A[0][kk], B, C[0][tbl], 0, 0, 0);
                C[1][tbl] = __builtin_amdgcn_mfma_f32_16x16x32_bf16(A[1][kk], B, C[1][tbl], 0, 0, 0);
            }
        }

        // bias + per-token sumsq (xor shuffles + cross-wave LDS)
        #pragma unroll
        for (int tbl = 0; tbl < 4; ++tbl) {
            float ss = 0.f;
            #pragma unroll
            for (int rg = 0; rg < 2; ++rg)
                #pragma unroll
                for (int r = 0; r < 4; ++r) {
                    C[rg][tbl][r] += bov[rg][r];
                    ss += C[rg][tbl][r] * C[rg][tbl][r];
                }
            ss += __shfl_xor(ss, 16, 64);
            ss += __shfl_xor(ss, 32, 64);
            if (lane < 16) part[w][tbl * 16 + lane] = ss;
        }
        __syncthreads();
        if (tid < 64) {
            float s = part[0][tid] + part[1][tid] + part[2][tid] + part[3][tid];
            scl[tid] = SQRT_C / fmaxf(sqrtf(s), 1e-12f);
        }
        __syncthreads();
        // stage scaled result to LDS [o][t]
        #pragma unroll
        for (int tbl = 0; tbl < 4; ++tbl) {
            float sc = scl[tbl * 16 + lm];
            #pragma unroll
            for (int rg = 0; rg < 2; ++rg)
                #pragma unroll
                for (int r = 0; r < 4; ++r)
                    ldsT[32 * w + rg * 16 + qd * 4 + r][tbl * 16 + lm] = C[rg][tbl][r] * sc * g2v[rg][r];
        }
        __syncthreads();
        // coalesced write-out: 16 lanes cover one o-row's 64 tokens (256 B)
        #pragma unroll
        for (int p = 0; p < 8; ++p) {
            const int o = p * 16 + (tid >> 4);
            const int c4 = (tid & 15) * 4;
            float4 v = *(const float4*)&ldsT[o][c4];
            *(float4*)(out + ((size_t)b * 128 + o) * NTOK + t0 + hb * 64 + c4) = v;
        }
        if (hb == 0) __syncthreads();   // protect part/scl/ldsT reuse
    }
}

extern "C" void kernel_launch(void* const* d_in, const int* in_sizes, int n_in,
                              void* d_out, int out_size, void* d_ws, size_t ws_size,
                              hipStream_t stream) {
    const float* x    = (const float*)d_in[0];
    const float* g1   = (const float*)d_in[1];
    const float* wqkv = (const float*)d_in[2];
    const float* wout = (const float*)d_in[3];
    const float* bo   = (const float*)d_in[4];
    const float* g2   = (const float*)d_in[5];
    float* out = (float*)d_out;
    char* ws = (char*)d_ws;
    // ws: qfrag bf16 [16][1024][4][512] @0 (67,108,864 B)
    //     pS fp32 [16][64][128]  @67,108,864 (524,288)
    //     pC fp32 [16][64][4096] @67,633,152 (16,777,216)
    //     MgT bf16 [16][128][128] @84,410,368 (524,288)
    //     wbf bf16 [384][128]     @84,934,656 (98,304)   total 85,032,960 B
    short* qfrag = (short*)ws;
    float* pS = (float*)(ws + 67108864);
    float* pC = (float*)(ws + 67633152);
    short* MgT = (short*)(ws + 84410368);
    short* wbf = (short*)(ws + 84934656);

    k0_cvt<<<192, 256, 0, stream>>>(wqkv, g1, wbf);
    k1_qkv<<<1024, 256, 0, stream>>>(x, wbf, qfrag, pS, pC);
    k2_ctx<<<256, 256, 0, stream>>>(pS, pC, wout, MgT);
    k3_out<<<2048, 256, 0, stream>>>(qfrag, MgT, bo, g2, out);
}

// Round 6
// 326.176 us; speedup vs baseline: 1.2659x; 1.0705x over previous
//
#include <hip/hip_runtime.h>
#include <hip/hip_bf16.h>

#define NTOK 16384
#define SQRT_C 11.313708498984761f
#define QSCALE 0.17677669529663687f
#define ROWP 152   // padded LDS row (shorts): 304 B = 76 dw == 12 banks, 16B-aligned

typedef __attribute__((ext_vector_type(8))) short v8s;   // 8 bf16 (4 VGPRs)
typedef __attribute__((ext_vector_type(4))) short v4s;   // 4 bf16 (8B)
typedef __attribute__((ext_vector_type(4))) float v4f;   // 4 fp32

__device__ inline short f2bf(float f) {
    __hip_bfloat16 h = __float2bfloat16(f);
    return __builtin_bit_cast(short, h);
}
__device__ inline float bf2f(short s) {
    unsigned u = ((unsigned)(unsigned short)s) << 16;
    return __builtin_bit_cast(float, u);
}
// LDS-only barrier: orders ds ops across waves WITHOUT draining vmcnt,
// so in-flight global loads stay outstanding across tile boundaries.
__device__ inline void lds_barrier() {
    __builtin_amdgcn_sched_barrier(0);
    asm volatile("s_waitcnt lgkmcnt(0)" ::: "memory");
    __builtin_amdgcn_s_barrier();
    __builtin_amdgcn_sched_barrier(0);
}

// ---------------- K0: wbf[o][c] = bf16(w_qkv[o][c] * g1[c])  (g1 folded) -------
__global__ void k0_cvt(const float* __restrict__ wq, const float* __restrict__ g1,
                       short* __restrict__ wbf) {
    int i = blockIdx.x * 256 + threadIdx.x;   // 49152
    wbf[i] = f2bf(wq[i] * g1[i & 127]);
}

// ---------------- K1: 8-wave blocks, W preloaded (48 rows/wave = 48 regs) ------
// grid 512 = 16 b x 32 chunks of 512 tokens; 512 thr (8 waves); 16 tiles of 32 t.
// Register budget: W 48 + xv 8 + temps ~30 arch; acc = C2[3][2] 24 + cacc[2] 8
// = 32  ->  total ~118 <= 128 cap from (512,4)  ->  2 blocks/CU (16 waves).
// Wave roles: w0-3: q head w (rg 2w,2w+1) + k rg (8+w); w4-7: rg 3w..3w+2 (k/v).
// exp(k) row sums via kvbuf re-read in (c) (1 reg) instead of accSr+shfl chain.
__global__ __launch_bounds__(512, 4) void k1_qkv(
    const float* __restrict__ x, const short* __restrict__ wbf,
    short* __restrict__ qfrag, float* __restrict__ pS, float* __restrict__ pC)
{
    __shared__ __align__(16) short xn[32][ROWP];    // bf16(x) [t][c]      9.7 KB
    __shared__ __align__(16) short kvbuf[256][40];  // exp(k) 0..127, v    20.5 KB
    __shared__ __align__(16) short qbufT[32][ROWP]; // q_soft bf16 [t][c]  9.7 KB
    __shared__ __align__(16) float nrm[8][32];      // per-wave sumsq      1 KB

    const int tid = threadIdx.x;
    const int lane = tid & 63;
    const int w = tid >> 6;            // wave 0..7
    const int qd = lane >> 4;          // quad 0..3
    const int lm = lane & 15;
    const int b = blockIdx.x >> 5;
    const int chunk = blockIdx.x & 31;
    const size_t xbase = (size_t)b * 128 * NTOK;
    const int crow = tid >> 3;         // channel sub-row 0..63
    const int tq4 = (tid & 7) * 4;     // token offset within tile
    const int h = w & 3, hi = w >> 2;

    // rg assignment (wave-uniform)
    const int rgl0 = (w < 4) ? 2 * w     : 3 * w;
    const int rgl1 = (w < 4) ? 2 * w + 1 : 3 * w + 1;
    const int rgl2 = (w < 4) ? 8 + w     : 3 * w + 2;

    // preload W A-fragments: 3 rg x 4 kk = 48 VGPRs
    v8s Wf[3][4];
    const short* wbase = wbf + lm * 128 + qd * 8;
    #pragma unroll
    for (int i = 0; i < 3; ++i) {
        const int rg = (i == 0) ? rgl0 : (i == 1) ? rgl1 : rgl2;
        #pragma unroll
        for (int kk = 0; kk < 4; ++kk)
            Wf[i][kk] = *(const v8s*)(wbase + rg * 2048 + kk * 32);
    }

    v4f cacc[2];
    cacc[0] = (v4f){0.f, 0.f, 0.f, 0.f};
    cacc[1] = (v4f){0.f, 0.f, 0.f, 0.f};
    float accS = 0.f;

    // x register buffer: thread holds channels {64p+crow}, tokens tq4..tq4+3
    v4f xv[2];
    auto loadx = [&](int tt) {
        #pragma unroll
        for (int p = 0; p < 2; ++p)
            xv[p] = *(const v4f*)(x + xbase + (size_t)(p * 64 + crow) * NTOK + tt + tq4);
    };
    loadx(chunk * 512);

    for (int st = 0; st < 16; ++st) {
        // ---- (a) sumsq reduce + bf16 convert + next-tile prefetch ----
        float s[4];
        #pragma unroll
        for (int j = 0; j < 4; ++j) {
            float v0 = xv[0][j], v1 = xv[1][j];
            s[j] = v0 * v0 + v1 * v1;
        }
        #pragma unroll
        for (int j = 0; j < 4; ++j) {
            s[j] += __shfl_xor(s[j], 8, 64);
            s[j] += __shfl_xor(s[j], 16, 64);
            s[j] += __shfl_xor(s[j], 32, 64);
        }
        if (lane < 8) *(v4f*)&nrm[w][lane * 4] = (v4f){s[0], s[1], s[2], s[3]};
        #pragma unroll
        for (int p = 0; p < 2; ++p)
            #pragma unroll
            for (int j = 0; j < 4; ++j)
                xn[tq4 + j][p * 64 + crow] = f2bf(xv[p][j]);
        if (st < 15) loadx(chunk * 512 + (st + 1) * 32);
        lds_barrier();

        // per-token rms scale for this lane's two columns (t = lm, 16+lm)
        float sA = 0.f, sB = 0.f;
        #pragma unroll
        for (int g = 0; g < 8; ++g) { sA += nrm[g][lm]; sB += nrm[g][16 + lm]; }
        const float scl0 = SQRT_C / fmaxf(sqrtf(sA), 1e-12f);
        const float scl1 = SQRT_C / fmaxf(sqrtf(sB), 1e-12f);

        // ---- (b) MFMA K=128 for 3 rg + distribute ----
        v4f C2[3][2];
        #pragma unroll
        for (int i = 0; i < 3; ++i) {
            C2[i][0] = (v4f){0.f, 0.f, 0.f, 0.f};
            C2[i][1] = (v4f){0.f, 0.f, 0.f, 0.f};
        }
        #pragma unroll
        for (int kk = 0; kk < 4; ++kk) {
            v8s B0 = *(const v8s*)&xn[lm][kk * 32 + qd * 8];
            v8s B1 = *(const v8s*)&xn[16 + lm][kk * 32 + qd * 8];
            #pragma unroll
            for (int i = 0; i < 3; ++i) {
                C2[i][0] = __builtin_amdgcn_mfma_f32_16x16x32_bf16(Wf[i][kk], B0, C2[i][0], 0, 0, 0);
                C2[i][1] = __builtin_amdgcn_mfma_f32_16x16x32_bf16(Wf[i][kk], B1, C2[i][1], 0, 0, 0);
            }
        }

        if (w < 4) {
            // q head w: softmax over d (rg pair), rows 32w..32w+31
            #pragma unroll
            for (int tg = 0; tg < 2; ++tg) {
                const float sclt = tg ? scl1 : scl0;
                float e0[4], e1[4];
                float m = -1e30f;
                #pragma unroll
                for (int r = 0; r < 4; ++r) {
                    e0[r] = C2[0][tg][r] * sclt;
                    e1[r] = C2[1][tg][r] * sclt;
                    m = fmaxf(m, fmaxf(e0[r], e1[r]));
                }
                m = fmaxf(m, __shfl_xor(m, 16, 64));
                m = fmaxf(m, __shfl_xor(m, 32, 64));
                float ssum = 0.f;
                #pragma unroll
                for (int r = 0; r < 4; ++r) {
                    e0[r] = __expf(e0[r] - m);
                    e1[r] = __expf(e1[r] - m);
                    ssum += e0[r] + e1[r];
                }
                ssum += __shfl_xor(ssum, 16, 64);
                ssum += __shfl_xor(ssum, 32, 64);
                const float inv = QSCALE / ssum;
                const int t = tg * 16 + lm;
                v4s p0, p1;
                #pragma unroll
                for (int r = 0; r < 4; ++r) {
                    p0[r] = f2bf(e0[r] * inv);
                    p1[r] = f2bf(e1[r] * inv);
                }
                *(v4s*)&qbufT[t][w * 32 + qd * 4] = p0;
                *(v4s*)&qbufT[t][w * 32 + 16 + qd * 4] = p1;
            }
            // k rg (8+w) -> kvbuf rows 16w..16w+15
            #pragma unroll
            for (int tg = 0; tg < 2; ++tg) {
                const float sclt = tg ? scl1 : scl0;
                const int col = tg * 16 + lm;
                #pragma unroll
                for (int r = 0; r < 4; ++r)
                    kvbuf[16 * w + qd * 4 + r][col] = f2bf(__expf(C2[2][tg][r] * sclt));
            }
        } else {
            // k/v rgs
            #pragma unroll
            for (int i = 0; i < 3; ++i) {
                const int rg = (i == 0) ? rgl0 : (i == 1) ? rgl1 : rgl2;
                const bool isk = rg < 16;
                const int kvr = isk ? (rg - 8) * 16 : 128 + (rg - 16) * 16;
                #pragma unroll
                for (int tg = 0; tg < 2; ++tg) {
                    const float sclt = tg ? scl1 : scl0;
                    const int col = tg * 16 + lm;
                    #pragma unroll
                    for (int r = 0; r < 4; ++r) {
                        float val = C2[i][tg][r] * sclt;
                        if (isk) val = __expf(val);
                        kvbuf[kvr + qd * 4 + r][col] = f2bf(val);
                    }
                }
            }
        }
        lds_barrier();

        // ---- (c) q gather + exp(k) row-sum partial + context MFMA ----
        {
            const int tb0 = chunk * 32 + st * 2;
            // q gather: wave w handles fragment (tbl=hi, kk=h)
            v8s pk = *(const v8s*)&qbufT[hi * 16 + lm][h * 32 + qd * 8];
            *(v8s*)(qfrag + ((((size_t)b * 1024 + tb0 + hi) * 4 + h) << 9) + lane * 8) = pk;
            // exp(k) row-sum: thread owns 8 cols of row tid>>2
            const int rowS = tid >> 2;
            v8s kvv = *(const v8s*)&kvbuf[rowS][(tid & 3) * 8];
            #pragma unroll
            for (int j = 0; j < 8; ++j) accS += bf2f(kvv[j]);
            // ctx head h, d-half hi
            v8s A  = *(const v8s*)&kvbuf[h * 32 + hi * 16 + lm][qd * 8];
            v8s B0 = *(const v8s*)&kvbuf[128 + h * 32 + lm][qd * 8];
            v8s B1 = *(const v8s*)&kvbuf[128 + h * 32 + 16 + lm][qd * 8];
            cacc[0] = __builtin_amdgcn_mfma_f32_16x16x32_bf16(A, B0, cacc[0], 0, 0, 0);
            cacc[1] = __builtin_amdgcn_mfma_f32_16x16x32_bf16(A, B1, cacc[1], 0, 0, 0);
        }
    }

    // epilogue: pS row sums (reduce 4 lanes sharing a row)
    {
        float aS = accS;
        aS += __shfl_xor(aS, 1, 64);
        aS += __shfl_xor(aS, 2, 64);
        if ((lane & 3) == 0) pS[(size_t)(b * 32 + chunk) * 128 + (tid >> 2)] = aS;
    }
    #pragma unroll
    for (int eg = 0; eg < 2; ++eg)
        #pragma unroll
        for (int r = 0; r < 4; ++r) {
            int d = hi * 16 + qd * 4 + r;
            int e = eg * 16 + lm;
            pC[(size_t)(b * 32 + chunk) * 4096 + h * 1024 + d * 32 + e] = cacc[eg][r];
        }
}

// ---------------- K2: reduce partials -> ctx -> MgT bf16 [b][o][c'] -------------
// grid 256 = 16 b x 4 h x 4 de-quarters
__global__ void k2_ctx(const float* __restrict__ pS, const float* __restrict__ pC,
                       const float* __restrict__ wout, short* __restrict__ MgT) {
    __shared__ float ctxq[8][33];
    __shared__ float Sv[32];
    const int tid = threadIdx.x;
    const int blk = blockIdx.x;
    const int qt = blk & 3, h = (blk >> 2) & 3, b = blk >> 4;
    if (tid < 32) {
        float s = 0.f;
        for (int ch = 0; ch < 32; ++ch) s += pS[(size_t)(b * 32 + ch) * 128 + h * 32 + tid];
        Sv[tid] = s;
    }
    __syncthreads();
    {
        int de = qt * 256 + tid;
        float s = 0.f;
        for (int ch = 0; ch < 32; ++ch) s += pC[(size_t)(b * 32 + ch) * 4096 + h * 1024 + de];
        ctxq[tid >> 5][tid & 31] = s / Sv[de >> 5];
    }
    __syncthreads();
    // MgT[o][h*32 + qt*8 + dl] = sum_e wout[o][h*32+e] * ctxq[dl][e]
    #pragma unroll
    for (int k = 0; k < 4; ++k) {
        int idx = tid + k * 256;           // 0..1023
        int o = idx >> 3, dl = idx & 7;
        float m = 0.f;
        #pragma unroll
        for (int e = 0; e < 32; ++e) m += wout[o * 128 + h * 32 + e] * ctxq[dl][e];
        MgT[((size_t)b * 128 + o) * 128 + h * 32 + qt * 8 + dl] = f2bf(m);
    }
}

// ---------------- K3: y = M_b @ q_soft + b_out -> rmsnorm(g2) (MFMA) ------------
// grid 2048 = 16 b x 128 chunks of 128 tokens; wave w owns rows 32w..32w+31.
// Two halves of 64 tokens; result staged through LDS [128][68] f32 so HBM
// writes are 256 B-contiguous per 16-lane group.
__global__ __launch_bounds__(256, 2) void k3_out(
    const short* __restrict__ qfrag, const short* __restrict__ MgT,
    const float* __restrict__ bo, const float* __restrict__ g2,
    float* __restrict__ out)
{
    __shared__ __align__(16) float ldsT[128][68];   // 34,816 B (row 272 B)
    __shared__ float part[4][64];
    __shared__ float scl[64];
    const int tid = threadIdx.x;
    const int lane = tid & 63, w = tid >> 6;
    const int qd = lane >> 4, lm = lane & 15;
    const int b = blockIdx.x >> 7;
    const int t0 = (blockIdx.x & 127) << 7;
    const int tb0 = t0 >> 4;

    v8s A[2][4];
    #pragma unroll
    for (int rg = 0; rg < 2; ++rg)
        #pragma unroll
        for (int kk = 0; kk < 4; ++kk)
            A[rg][kk] = *(const v8s*)(MgT + ((size_t)b * 128 + 32 * w + rg * 16 + lm) * 128 + kk * 32 + qd * 8);

    float bov[2][4], g2v[2][4];
    #pragma unroll
    for (int rg = 0; rg < 2; ++rg)
        #pragma unroll
        for (int r = 0; r < 4; ++r) {
            int o = 32 * w + rg * 16 + qd * 4 + r;
            bov[rg][r] = bo[o];
            g2v[rg][r] = g2[o];
        }

    #pragma unroll
    for (int hb = 0; hb < 2; ++hb) {
        v4f C[2][4];
        #pragma unroll
        for (int rg = 0; rg < 2; ++rg)
            #pragma unroll
            for (int tbl = 0; tbl < 4; ++tbl)
                C[rg][tbl] = (v4f){0.f, 0.f, 0.f, 0.f};

        #pragma unroll
        for (int tbl = 0; tbl < 4; ++tbl) {
            const int tb = hb * 4 + tbl;
            #pragma unroll
            for (int kk = 0; kk < 4; ++kk) {
                v8s B = *(const v8s*)(qfrag + ((((size_t)b * 1024 + tb0 + tb) * 4 + kk) << 9) + lane * 8);
                C[0][tbl] = __builtin_amdgcn_mfma_f32_16x16x32_bf16(A[0][kk], B, C[0][tbl], 0, 0, 0);
                C[1][tbl] = __builtin_amdgcn_mfma_f32_16x16x32_bf16(A[1][kk], B, C[1][tbl], 0, 0, 0);
            }
        }

        // bias + per-token sumsq (xor shuffles + cross-wave LDS)
        #pragma unroll
        for (int tbl = 0; tbl < 4; ++tbl) {
            float ss = 0.f;
            #pragma unroll
            for (int rg = 0; rg < 2; ++rg)
                #pragma unroll
                for (int r = 0; r < 4; ++r) {
                    C[rg][tbl][r] += bov[rg][r];
                    ss += C[rg][tbl][r] * C[rg][tbl][r];
                }
            ss += __shfl_xor(ss, 16, 64);
            ss += __shfl_xor(ss, 32, 64);
            if (lane < 16) part[w][tbl * 16 + lane] = ss;
        }
        __syncthreads();
        if (tid < 64) {
            float s = part[0][tid] + part[1][tid] + part[2][tid] + part[3][tid];
            scl[tid] = SQRT_C / fmaxf(sqrtf(s), 1e-12f);
        }
        __syncthreads();
        // stage scaled result to LDS [o][t]
        #pragma unroll
        for (int tbl = 0; tbl < 4; ++tbl) {
            float sc = scl[tbl * 16 + lm];
            #pragma unroll
            for (int rg = 0; rg < 2; ++rg)
                #pragma unroll
                for (int r = 0; r < 4; ++r)
                    ldsT[32 * w + rg * 16 + qd * 4 + r][tbl * 16 + lm] = C[rg][tbl][r] * sc * g2v[rg][r];
        }
        __syncthreads();
        // coalesced write-out: 16 lanes cover one o-row's 64 tokens (256 B)
        #pragma unroll
        for (int p = 0; p < 8; ++p) {
            const int o = p * 16 + (tid >> 4);
            const int c4 = (tid & 15) * 4;
            float4 v = *(const float4*)&ldsT[o][c4];
            *(float4*)(out + ((size_t)b * 128 + o) * NTOK + t0 + hb * 64 + c4) = v;
        }
        if (hb == 0) __syncthreads();   // protect part/scl/ldsT reuse
    }
}

extern "C" void kernel_launch(void* const* d_in, const int* in_sizes, int n_in,
                              void* d_out, int out_size, void* d_ws, size_t ws_size,
                              hipStream_t stream) {
    const float* x    = (const float*)d_in[0];
    const float* g1   = (const float*)d_in[1];
    const float* wqkv = (const float*)d_in[2];
    const float* wout = (const float*)d_in[3];
    const float* bo   = (const float*)d_in[4];
    const float* g2   = (const float*)d_in[5];
    float* out = (float*)d_out;
    char* ws = (char*)d_ws;
    // ws: qfrag bf16 [16][1024][4][512] @0 (67,108,864 B)
    //     pS fp32 [16][32][128]  @67,108,864 (262,144)
    //     pC fp32 [16][32][4096] @67,371,008 (8,388,608)
    //     MgT bf16 [16][128][128] @75,759,616 (524,288)
    //     wbf bf16 [384][128]     @76,283,904 (98,304)   total 76,382,208 B
    short* qfrag = (short*)ws;
    float* pS = (float*)(ws + 67108864);
    float* pC = (float*)(ws + 67371008);
    short* MgT = (short*)(ws + 75759616);
    short* wbf = (short*)(ws + 76283904);

    k0_cvt<<<192, 256, 0, stream>>>(wqkv, g1, wbf);
    k1_qkv<<<512, 512, 0, stream>>>(x, wbf, qfrag, pS, pC);
    k2_ctx<<<256, 256, 0, stream>>>(pS, pC, wout, MgT);
    k3_out<<<2048, 256, 0, stream>>>(qfrag, MgT, bo, g2, out);
}